// Round 6
// baseline (407.972 us; speedup 1.0000x reference)
//
#include <hip/hip_runtime.h>
#include <hip/hip_bf16.h>

#define EMBED 1024
#define THREE_EMBED 3072
#define NHEAD 16
#define HDIM 64
#define MTOT 16384
#define LTOT 16383

typedef __attribute__((ext_vector_type(8))) short bf16x8;
typedef __attribute__((ext_vector_type(4))) float f32x4;

__device__ __forceinline__ unsigned short f2b(float f) {
  union { float f; unsigned u; } v; v.f = f;
  unsigned r = v.u + 0x7fffu + ((v.u >> 16) & 1u);
  return (unsigned short)(r >> 16);
}
__device__ __forceinline__ float b2f(unsigned short h) {
  union { unsigned u; float f; } v; v.u = ((unsigned)h) << 16;
  return v.f;
}

__device__ __forceinline__ void gload16(const void* g, void* l) {
  __builtin_amdgcn_global_load_lds(
      (const __attribute__((address_space(1))) void*)g,
      (__attribute__((address_space(3))) void*)l, 16, 0, 0);
}

#define BARRIER() asm volatile("s_barrier" ::: "memory")

// ---------------------------------------------------------------------------
// cast pass: x (+padding) -> xb bf16; qkv_w -> wqb; optional proj_w -> wpb
// (np = proj elements/8, 0 when not fused); inv[kvi[i]] = i.
// ---------------------------------------------------------------------------
__global__ __launch_bounds__(256) void cast_inputs(
    const float* __restrict__ x, const float* __restrict__ padding,
    const float* __restrict__ wq, const float* __restrict__ wp,
    const int* __restrict__ kvi,
    unsigned short* __restrict__ xb, unsigned short* __restrict__ wqb,
    unsigned short* __restrict__ wpb, int* __restrict__ inv, int np)
{
  const int NX = MTOT * EMBED / 8;
  const int NQ = THREE_EMBED * EMBED / 8;
  const int total = NX + NQ + np;
  int g = blockIdx.x * 256 + threadIdx.x;
  const int stride = gridDim.x * 256;
  for (; g < total + MTOT; g += stride) {
    if (g >= total) {
      int i = g - total;
      inv[kvi[i]] = i;
      continue;
    }
    const float* src;
    unsigned short* dst;
    if (g < NX) {
      size_t e = (size_t)g * 8;
      int row = (int)(e >> 10);
      src = (row < LTOT) ? (x + e) : (padding + (e - (size_t)LTOT * 1024));
      dst = xb + e;
    } else if (g < NX + NQ) {
      size_t e = (size_t)(g - NX) * 8;
      src = wq + e;
      dst = wqb + e;
    } else {
      size_t e = (size_t)(g - NX - NQ) * 8;
      src = wp + e;
      dst = wpb + e;
    }
    float4 a = *(const float4*)src;
    float4 b = *(const float4*)(src + 4);
    ushort4 u0, u1;
    u0.x = f2b(a.x); u0.y = f2b(a.y); u0.z = f2b(a.z); u0.w = f2b(a.w);
    u1.x = f2b(b.x); u1.y = f2b(b.y); u1.z = f2b(b.z); u1.w = f2b(b.w);
    *(ushort4*)dst = u0;
    *(ushort4*)(dst + 4) = u1;
  }
}

// ---------------------------------------------------------------------------
// 256x256 8-phase GEMM (T2+T3+T4+T5), C = A @ B^T + bias.
// 512 threads = 8 waves as 2(M)x4(N); per-wave output 128x64; BK=64.
// 2-K-tile unrolled body, compile-time buffer parity.
// Phase rebalance: phases are (kstep x mt-group) so ds_read bursts
// are 8/4/8/4 (was 12/4/4/4) and only 4 b-frags live at a time (-16 VGPR):
//   p0: read b@ks0 + a(mt0-3)@ks0; stage (t+1)A0 | BAR | MFMA | BAR
//   p1: read a(mt4-7)@ks0;         stage (t+1)A1 | BAR | MFMA | BAR
//   p2: read b@ks1 + a(mt0-3)@ks1; stage (t+2)B0 | BAR | MFMA | BAR
//   p3: read a(mt4-7)@ks1;         stage (t+2)B1 | BAR | MFMA | vmcnt | BAR
// Per-accumulator order identical to round 4 (ks0 then ks1 into acc[m][n]).
// EPI=0: bias + scatter via inv[] to head-major qkvh bf16 (gemm_qkv).
// EPI=1: bias + fp32 row-scatter via kvi[] with kvi<LTOT guard (gemm_proj).
// ---------------------------------------------------------------------------
template <int EPI>
__global__ __launch_bounds__(512, 2) void gemm256(
    const unsigned short* __restrict__ A, const unsigned short* __restrict__ B,
    const float* __restrict__ bias, const int* __restrict__ idx,
    unsigned short* __restrict__ outb, float* __restrict__ outf)
{
  __shared__ __align__(16) unsigned short lds[65536];  // 128 KiB
  const int t = threadIdx.x;
  const int lane = t & 63, wid = t >> 6;
  const int l15 = lane & 15, quad = lane >> 4;
  const int wr = wid >> 2, wc = wid & 3;
  const int bm = blockIdx.x, bn = blockIdx.y;

  // staging: linear LDS dest + inverse-swizzled global source (rule #21)
  const int srow = wid * 8 + (lane >> 3);
  const int scol = ((lane & 7) ^ (lane >> 3)) * 8;
  const unsigned short* gA = A + (size_t)(bm * 256 + srow) * EMBED + scol;
  const unsigned short* gB = B + (size_t)(bn * 256 + srow) * EMBED + scol;

  auto stA = [&](int p, int R0, int kt) {
    const unsigned short* g = gA + (size_t)R0 * EMBED + kt * 64;
    char* d = (char*)lds + p * 32768 + R0 * 128 + wid * 1024;
    gload16(g, d);
    gload16(g + (size_t)64 * EMBED, d + 8192);
  };
  auto stB = [&](int p, int R0, int kt) {
    const unsigned short* g = gB + (size_t)R0 * EMBED + kt * 64;
    char* d = (char*)lds + 65536 + p * 32768 + R0 * 128 + wid * 1024;
    gload16(g, d);
    gload16(g + (size_t)64 * EMBED, d + 8192);
  };

  const int aOff = (wr * 128 + l15) * 64;
  const int bOff = (wc * 64 + l15) * 64;
  const int swz0 = (quad ^ (l15 & 7)) * 8;
  const int swz1 = ((quad + 4) ^ (l15 & 7)) * 8;

  f32x4 acc[8][4];
#pragma unroll
  for (int i = 0; i < 8; ++i)
#pragma unroll
    for (int j = 0; j < 4; ++j) acc[i][j] = (f32x4){0.f, 0.f, 0.f, 0.f};

  // prologue: tile0 (A0,A1,B0,B1) + tile1 (B0,B1); vmcnt(4) keeps tile1's
  // B pair in flight.
  stA(0, 0, 0); stA(0, 128, 0); stB(0, 0, 0); stB(0, 128, 0);
  stB(1, 0, 1); stB(1, 128, 1);
  asm volatile("s_waitcnt vmcnt(4)" ::: "memory");
  BARRIER();

#define MFMAGRP(MB)                                                          \
  _Pragma("unroll") for (int m = 0; m < 4; ++m)                              \
      _Pragma("unroll") for (int n = 0; n < 4; ++n)                          \
          acc[(MB) + m][n] = __builtin_amdgcn_mfma_f32_16x16x32_bf16(        \
              a[m], b[n], acc[(MB) + m][n], 0, 0, 0);

  // One K-tile with compile-time parity P. STA/STB/WCNT are literals.
#define TILE(P, KT, STA, STB, WCNT)                                          \
  {                                                                          \
    const unsigned short* Ab = lds + (P) * 16384 + aOff;                     \
    const unsigned short* Bb = lds + 32768 + (P) * 16384 + bOff;             \
    bf16x8 a[4], b[4];                                                       \
    { /* phase 0: ks0, mt0-3 */                                              \
      _Pragma("unroll") for (int n = 0; n < 4; ++n)                          \
          b[n] = *(const bf16x8*)(Bb + n * 1024 + swz0);                     \
      _Pragma("unroll") for (int m = 0; m < 4; ++m)                          \
          a[m] = *(const bf16x8*)(Ab + m * 1024 + swz0);                     \
      if (STA) stA((P) ^ 1, 0, (KT) + 1);                                    \
      BARRIER();                                                             \
      __builtin_amdgcn_s_setprio(1);                                         \
      MFMAGRP(0);                                                            \
      __builtin_amdgcn_s_setprio(0);                                         \
      BARRIER();                                                             \
    }                                                                        \
    { /* phase 1: ks0, mt4-7 */                                              \
      _Pragma("unroll") for (int m = 0; m < 4; ++m)                          \
          a[m] = *(const bf16x8*)(Ab + (4 + m) * 1024 + swz0);               \
      if (STA) stA((P) ^ 1, 128, (KT) + 1);                                  \
      BARRIER();                                                             \
      __builtin_amdgcn_s_setprio(1);                                         \
      MFMAGRP(4);                                                            \
      __builtin_amdgcn_s_setprio(0);                                         \
      BARRIER();                                                             \
    }                                                                        \
    { /* phase 2: ks1, mt0-3 */                                              \
      _Pragma("unroll") for (int n = 0; n < 4; ++n)                          \
          b[n] = *(const bf16x8*)(Bb + n * 1024 + swz1);                     \
      _Pragma("unroll") for (int m = 0; m < 4; ++m)                          \
          a[m] = *(const bf16x8*)(Ab + m * 1024 + swz1);                     \
      if (STB) stB((P), 0, (KT) + 2);                                        \
      BARRIER();                                                             \
      __builtin_amdgcn_s_setprio(1);                                         \
      MFMAGRP(0);                                                            \
      __builtin_amdgcn_s_setprio(0);                                         \
      BARRIER();                                                             \
    }                                                                        \
    { /* phase 3: ks1, mt4-7 */                                              \
      _Pragma("unroll") for (int m = 0; m < 4; ++m)                          \
          a[m] = *(const bf16x8*)(Ab + (4 + m) * 1024 + swz1);               \
      if (STB) stB((P), 128, (KT) + 2);                                      \
      BARRIER();                                                             \
      __builtin_amdgcn_s_setprio(1);                                         \
      MFMAGRP(4);                                                            \
      __builtin_amdgcn_s_setprio(0);                                         \
      if ((WCNT) == 4) asm volatile("s_waitcnt vmcnt(4)" ::: "memory");      \
      if ((WCNT) == 0) asm volatile("s_waitcnt vmcnt(0)" ::: "memory");      \
      BARRIER();                                                             \
    }                                                                        \
  }

#pragma unroll 1
  for (int t2 = 0; t2 < 7; ++t2) {
    const int kt = t2 * 2;
    TILE(0, kt, 1, 1, 4);
    TILE(1, kt + 1, 1, 1, 4);
  }
  // tail: tile 14 stages tile 15's A then drains; tile 15 computes clean.
  TILE(0, 14, 1, 0, 0);
  TILE(1, 15, 0, 0, -1);
#undef TILE
#undef MFMAGRP

  // epilogue
  float bv[4];
#pragma unroll
  for (int nt = 0; nt < 4; ++nt)
    bv[nt] = bias[bn * 256 + wc * 64 + nt * 16 + l15];
  if constexpr (EPI == 0) {
    const int hh = bn * 4 + wc;  // wave's 64-col span == one (part,head) slot
    unsigned short* buf = outb + (size_t)hh * (MTOT * HDIM);
#pragma unroll
    for (int mt = 0; mt < 8; ++mt) {
#pragma unroll
      for (int reg = 0; reg < 4; ++reg) {
        int row = bm * 256 + wr * 128 + mt * 16 + quad * 4 + reg;
        int i = idx[row];  // inv[]
#pragma unroll
        for (int nt = 0; nt < 4; ++nt)
          buf[(size_t)i * HDIM + nt * 16 + l15] =
              f2b(acc[mt][nt][reg] + bv[nt]);
      }
    }
  } else {
    const int col = bn * 256 + wc * 64;
#pragma unroll
    for (int mt = 0; mt < 8; ++mt) {
#pragma unroll
      for (int reg = 0; reg < 4; ++reg) {
        int i = bm * 256 + wr * 128 + mt * 16 + quad * 4 + reg;
        int orow = idx[i];  // kvi[]
        if (orow < LTOT) {
#pragma unroll
          for (int nt = 0; nt < 4; ++nt)
            outf[(size_t)orow * EMBED + col + nt * 16 + l15] =
                acc[mt][nt][reg] + bv[nt];
        }
      }
    }
  }
}

// ---------------------------------------------------------------------------
// cast_w: proj_w fp32 -> bf16 (fallback path when ws has no spare region).
// ---------------------------------------------------------------------------
__global__ __launch_bounds__(256) void cast_w(
    const float* __restrict__ w, unsigned short* __restrict__ wb)
{
  int g = blockIdx.x * 256 + threadIdx.x;
  size_t e = (size_t)g * 8;
  float4 a = *(const float4*)(w + e);
  float4 b = *(const float4*)(w + e + 4);
  ushort4 u0, u1;
  u0.x = f2b(a.x); u0.y = f2b(a.y); u0.z = f2b(a.z); u0.w = f2b(a.w);
  u1.x = f2b(b.x); u1.y = f2b(b.y); u1.z = f2b(b.z); u1.w = f2b(b.w);
  *(ushort4*)(wb + e) = u0;
  *(ushort4*)(wb + e + 4) = u1;
}

// ---------------------------------------------------------------------------
// Attention: one block per (window, head). RoPE fused in
// (rope_qk kernel deleted):
//  - Q roped in-register at load: qa[qt][0]/[1] are exactly the rotation
//    pair (d, d+32); SCALE=0.125 folded in. Rounding sequence identical to
//    the old rope_qk path (bf16 -> f32 rope -> bf16).
//  - K roped during LDS staging: thread covers d in {hx*16..+16} and the
//    partner {+32..+48}, so it owns both rotation halves; stores go to the
//    same swizzled chunk slots as before.
//  - V untouched. Tables are L2-resident (8.4 MB, shared across 16 heads).
// Output in window-permuted order (ow); kvi scatter lives in gemm_proj.
// ---------------------------------------------------------------------------
__global__ __launch_bounds__(256, 3) void attn(
    const unsigned short* __restrict__ qkvh,
    const float* __restrict__ rope_cos, const float* __restrict__ rope_sin,
    unsigned short* __restrict__ ow)
{
  __shared__ __align__(16) unsigned short sK[128 * 64];
  __shared__ __align__(16) unsigned short sV[64 * 128];
  __shared__ __align__(16) unsigned short sP[4][16 * 40];

  const int t = threadIdx.x;
  const int lane = t & 63, wid = t >> 6;
  const int l15 = lane & 15, quad = lane >> 4;
  const int wwin = blockIdx.x >> 4;
  const int h = blockIdx.x & 15;

  const unsigned short* Qh = qkvh + (size_t)h * (MTOT * HDIM);
  const unsigned short* Kh = qkvh + (size_t)(16 + h) * (MTOT * HDIM);
  const unsigned short* Vh = qkvh + (size_t)(32 + h) * (MTOT * HDIM);

  f32x4 accO[4][4];
  float mrow[4][4], lrow[4][4];
#pragma unroll
  for (int qt = 0; qt < 4; ++qt) {
#pragma unroll
    for (int nt = 0; nt < 4; ++nt) accO[qt][nt] = (f32x4){0.f, 0.f, 0.f, 0.f};
#pragma unroll
    for (int reg = 0; reg < 4; ++reg) { mrow[qt][reg] = -1e30f; lrow[qt][reg] = 0.f; }
  }

  // Q load + in-register RoPE (pair is (d, d+32) = qa[qt][0]/qa[qt][1])
  bf16x8 qa[4][2];
#pragma unroll
  for (int qt = 0; qt < 4; ++qt) {
    int i = wwin * 256 + wid * 64 + qt * 16 + l15;
    const unsigned short* qp = Qh + (size_t)i * HDIM;
    const float* cp = rope_cos + (size_t)i * HDIM + quad * 8;
    const float* sp = rope_sin + (size_t)i * HDIM + quad * 8;
    bf16x8 qlo = *(const bf16x8*)(qp + quad * 8);
    bf16x8 qhi = *(const bf16x8*)(qp + 32 + quad * 8);
    float cl[8], ch[8], sl[8], sh[8];
    *(float4*)(cl)     = *(const float4*)(cp);
    *(float4*)(cl + 4) = *(const float4*)(cp + 4);
    *(float4*)(ch)     = *(const float4*)(cp + 32);
    *(float4*)(ch + 4) = *(const float4*)(cp + 36);
    *(float4*)(sl)     = *(const float4*)(sp);
    *(float4*)(sl + 4) = *(const float4*)(sp + 4);
    *(float4*)(sh)     = *(const float4*)(sp + 32);
    *(float4*)(sh + 4) = *(const float4*)(sp + 36);
#pragma unroll
    for (int j = 0; j < 8; ++j) {
      float a = b2f((unsigned short)qlo[j]);
      float b = b2f((unsigned short)qhi[j]);
      qa[qt][0][j] = (short)f2b((a * cl[j] - b * sl[j]) * 0.125f);
      qa[qt][1][j] = (short)f2b((b * ch[j] + a * sh[j]) * 0.125f);
    }
  }

  for (int half = 0; half < 2; ++half) {
    __syncthreads();
    {
      int key = t >> 1, hx = t & 1;
      int i = wwin * 256 + half * 128 + key;
      int k7 = key & 7;
      // K staging with fused RoPE: this thread owns d in
      // [hx*16, hx*16+16) and partners [+32, +48) -> chunks
      // {hx*2, hx*2+1} and {hx*2+4, hx*2+5}.
      const unsigned short* kp = Kh + (size_t)i * HDIM;
      const float* cp = rope_cos + (size_t)i * HDIM;
      const float* sp = rope_sin + (size_t)i * HDIM;
#pragma unroll
      for (int cc = 0; cc < 2; ++cc) {
        int dlo = hx * 16 + cc * 8;
        int dhi = dlo + 32;
        bf16x8 klo = *(const bf16x8*)(kp + dlo);
        bf16x8 khi = *(const bf16x8*)(kp + dhi);
        float cl[8], ch[8], sl[8], sh[8];
        *(float4*)(cl)     = *(const float4*)(cp + dlo);
        *(float4*)(cl + 4) = *(const float4*)(cp + dlo + 4);
        *(float4*)(ch)     = *(const float4*)(cp + dhi);
        *(float4*)(ch + 4) = *(const float4*)(cp + dhi + 4);
        *(float4*)(sl)     = *(const float4*)(sp + dlo);
        *(float4*)(sl + 4) = *(const float4*)(sp + dlo + 4);
        *(float4*)(sh)     = *(const float4*)(sp + dhi);
        *(float4*)(sh + 4) = *(const float4*)(sp + dhi + 4);
        bf16x8 olo, ohi;
#pragma unroll
        for (int j = 0; j < 8; ++j) {
          float a = b2f((unsigned short)klo[j]);
          float b = b2f((unsigned short)khi[j]);
          olo[j] = (short)f2b(a * cl[j] - b * sl[j]);
          ohi[j] = (short)f2b(b * ch[j] + a * sh[j]);
        }
        int clo = dlo >> 3;       // 0..3
        int chi = dhi >> 3;       // 4..7
        *(uint4*)(sK + key * 64 + ((clo ^ k7) * 8)) = *(uint4*)&olo;
        *(uint4*)(sK + key * 64 + ((chi ^ k7) * 8)) = *(uint4*)&ohi;
      }
      // V staging (no rope), unchanged
      const unsigned short* vp = Vh + (size_t)i * HDIM + hx * 32;
      int kc3 = key >> 3;
#pragma unroll
      for (int c = 0; c < 4; ++c) {
        bf16x8 va = *(const bf16x8*)(vp + c * 8);
#pragma unroll
        for (int j = 0; j < 8; ++j) {
          int d = hx * 32 + c * 8 + j;
          sV[d * 128 + ((kc3 ^ (d & 7)) * 8) + (key & 7)] =
              (unsigned short)va[j];
        }
      }
    }
    __syncthreads();

#pragma unroll
    for (int qt = 0; qt < 4; ++qt) {
      f32x4 accS[8];
#pragma unroll
      for (int nt = 0; nt < 8; ++nt) accS[nt] = (f32x4){0.f, 0.f, 0.f, 0.f};
#pragma unroll
      for (int ks = 0; ks < 2; ++ks) {
#pragma unroll
        for (int nt = 0; nt < 8; ++nt) {
          int key = nt * 16 + l15;
          bf16x8 bk = *(const bf16x8*)(
              sK + key * 64 + (((ks * 4 + quad) ^ (key & 7)) * 8));
          accS[nt] = __builtin_amdgcn_mfma_f32_16x16x32_bf16(
              qa[qt][ks], bk, accS[nt], 0, 0, 0);
        }
      }
#pragma unroll
      for (int reg = 0; reg < 4; ++reg) {
        float mx = accS[0][reg];
#pragma unroll
        for (int nt = 1; nt < 8; ++nt) mx = fmaxf(mx, accS[nt][reg]);
#pragma unroll
        for (int off = 1; off < 16; off <<= 1)
          mx = fmaxf(mx, __shfl_xor(mx, off, 64));
        float mold = mrow[qt][reg];
        float mnew = fmaxf(mold, mx);
        float alpha = __expf(mold - mnew);
        mrow[qt][reg] = mnew;
        float ls = 0.f;
#pragma unroll
        for (int nt = 0; nt < 8; ++nt) {
          float p = __expf(accS[nt][reg] - mnew);
          accS[nt][reg] = p;
          ls += p;
        }
#pragma unroll
        for (int off = 1; off < 16; off <<= 1) ls += __shfl_xor(ls, off, 64);
        lrow[qt][reg] = lrow[qt][reg] * alpha + ls;
#pragma unroll
        for (int nt = 0; nt < 4; ++nt) accO[qt][nt][reg] *= alpha;
      }
#pragma unroll
      for (int kc = 0; kc < 4; ++kc) {
#pragma unroll
        for (int nt2 = 0; nt2 < 2; ++nt2) {
#pragma unroll
          for (int reg = 0; reg < 4; ++reg) {
            sP[wid][(quad * 4 + reg) * 40 + nt2 * 16 + l15] =
                f2b(accS[kc * 2 + nt2][reg]);
          }
        }
        bf16x8 pa = *(const bf16x8*)(&sP[wid][l15 * 40 + quad * 8]);
#pragma unroll
        for (int nt = 0; nt < 4; ++nt) {
          int d = nt * 16 + l15;
          bf16x8 bv = *(const bf16x8*)(
              sV + d * 128 + (((kc * 4 + quad) ^ (d & 7)) * 8));
          accO[qt][nt] = __builtin_amdgcn_mfma_f32_16x16x32_bf16(
              pa, bv, accO[qt][nt], 0, 0, 0);
        }
      }
    }
  }

  // ---- vectorized epilogue: per-wave LDS transpose, 16B/lane stores ----
  __syncthreads();                         // all compute done; sK = scratch
  unsigned short* scr = sK + wid * 2048;   // 4 KB per wave, stride-72 rows
  const int rlane = lane >> 3;             // 0..7
  const int clane = (lane & 7) * 8;        // col chunk (shorts)
#pragma unroll
  for (int qt = 0; qt < 4; ++qt) {
#pragma unroll
    for (int reg = 0; reg < 4; ++reg) {
      float invl = 1.0f / lrow[qt][reg];
      int r = quad * 4 + reg;
#pragma unroll
      for (int nt = 0; nt < 4; ++nt)
        scr[r * 72 + nt * 16 + l15] = f2b(accO[qt][nt][reg] * invl);
    }
    // wave-local scratch: compiler orders the LDS ops (same base pointer)
#pragma unroll
    for (int rr = 0; rr < 2; ++rr) {
      int row = rr * 8 + rlane;
      bf16x8 vv = *(const bf16x8*)(scr + row * 72 + clane);
      int i = wwin * 256 + wid * 64 + qt * 16 + row;
      *(bf16x8*)(ow + (size_t)i * EMBED + h * HDIM + clane) = vv;
    }
  }
}

// ---------------------------------------------------------------------------
extern "C" void kernel_launch(void* const* d_in, const int* in_sizes, int n_in,
                              void* d_out, int out_size, void* d_ws, size_t ws_size,
                              hipStream_t stream) {
  const float* x        = (const float*)d_in[0];
  const float* qkv_w    = (const float*)d_in[1];
  const float* qkv_b    = (const float*)d_in[2];
  const float* proj_w   = (const float*)d_in[3];
  const float* proj_b   = (const float*)d_in[4];
  const float* padding  = (const float*)d_in[5];
  const float* rope_cos = (const float*)d_in[6];
  const float* rope_sin = (const float*)d_in[7];
  const int*   kvi      = (const int*)d_in[8];

  // ws layout:
  //   [0, 100.66M):       qkvh — head-major, window-permuted [48][16384][64]
  //                       bf16 (un-roped; attn ropes Q/K on the fly).
  //   [100.66M, +33.55M): xb (cast+gemm_qkv) then ow (attn output,
  //                       window-permuted [16384][1024] bf16, gemm_proj A)
  //   [134.22M, +2M):     wpb (proj_w bf16) IF ws_size permits; else wpb
  //                       falls back to the dead Q region + cast_w launch.
  // d_out scratch: head: wqb (6.3 MB); tail: inv (64 KB int32) — both read
  // only by gemm_qkv, which completes before gemm_proj (stream order).
  const size_t QKVH_B = (size_t)MTOT * THREE_EMBED * 2;   // 100,663,296
  const size_t R_B    = (size_t)MTOT * EMBED * 2;         //  33,554,432
  const size_t W_B    = (size_t)EMBED * EMBED * 2;        //   2,097,152
  unsigned short* qkvh = (unsigned short*)d_ws;
  unsigned short* R    = (unsigned short*)((char*)d_ws + QKVH_B);
  unsigned short* xb = R;
  unsigned short* ow = R;
  unsigned short* wqb = (unsigned short*)d_out;
  const bool roomy = ws_size >= QKVH_B + R_B + W_B;
  unsigned short* wpb = roomy
      ? (unsigned short*)((char*)d_ws + QKVH_B + R_B)
      : qkvh;  // Q region, dead after attn (fallback)
  int* inv = (int*)((char*)d_out + (size_t)LTOT * EMBED * 4 - (size_t)MTOT * 4);
  float* out = (float*)d_out;

  cast_inputs<<<4096, 256, 0, stream>>>(
      x, padding, qkv_w, roomy ? proj_w : nullptr, kvi, xb, wqb, wpb, inv,
      roomy ? (EMBED * EMBED / 8) : 0);
  gemm256<0><<<dim3(64, 12), 512, 0, stream>>>(xb, wqb, qkv_b, inv, qkvh,
                                               nullptr);
  attn<<<dim3(64 * 16), 256, 0, stream>>>(qkvh, rope_cos, rope_sin, ow);
  if (!roomy) cast_w<<<512, 256, 0, stream>>>(proj_w, wpb);
  gemm256<1><<<dim3(64, 4), 512, 0, stream>>>(ow, wpb, proj_b, kvi, nullptr,
                                              out);
}

// Round 7
// 366.293 us; speedup vs baseline: 1.1138x; 1.1138x over previous
//
#include <hip/hip_runtime.h>
#include <hip/hip_bf16.h>

#define EMBED 1024
#define THREE_EMBED 3072
#define NHEAD 16
#define HDIM 64
#define MTOT 16384
#define LTOT 16383

typedef __attribute__((ext_vector_type(8))) short bf16x8;
typedef __attribute__((ext_vector_type(4))) float f32x4;

__device__ __forceinline__ unsigned short f2b(float f) {
  union { float f; unsigned u; } v; v.f = f;
  unsigned r = v.u + 0x7fffu + ((v.u >> 16) & 1u);
  return (unsigned short)(r >> 16);
}
__device__ __forceinline__ float b2f(unsigned short h) {
  union { unsigned u; float f; } v; v.u = ((unsigned)h) << 16;
  return v.f;
}

__device__ __forceinline__ void gload16(const void* g, void* l) {
  __builtin_amdgcn_global_load_lds(
      (const __attribute__((address_space(1))) void*)g,
      (__attribute__((address_space(3))) void*)l, 16, 0, 0);
}

#define BARRIER() asm volatile("s_barrier" ::: "memory")

// ---------------------------------------------------------------------------
// cast pass: x (+padding) -> xb bf16; qkv_w -> wqb; optional proj_w -> wpb
// (np = proj elements/8, 0 when not fused); inv[kvi[i]] = i.
// ---------------------------------------------------------------------------
__global__ __launch_bounds__(256) void cast_inputs(
    const float* __restrict__ x, const float* __restrict__ padding,
    const float* __restrict__ wq, const float* __restrict__ wp,
    const int* __restrict__ kvi,
    unsigned short* __restrict__ xb, unsigned short* __restrict__ wqb,
    unsigned short* __restrict__ wpb, int* __restrict__ inv, int np)
{
  const int NX = MTOT * EMBED / 8;
  const int NQ = THREE_EMBED * EMBED / 8;
  const int total = NX + NQ + np;
  int g = blockIdx.x * 256 + threadIdx.x;
  const int stride = gridDim.x * 256;
  for (; g < total + MTOT; g += stride) {
    if (g >= total) {
      int i = g - total;
      inv[kvi[i]] = i;
      continue;
    }
    const float* src;
    unsigned short* dst;
    if (g < NX) {
      size_t e = (size_t)g * 8;
      int row = (int)(e >> 10);
      src = (row < LTOT) ? (x + e) : (padding + (e - (size_t)LTOT * 1024));
      dst = xb + e;
    } else if (g < NX + NQ) {
      size_t e = (size_t)(g - NX) * 8;
      src = wq + e;
      dst = wqb + e;
    } else {
      size_t e = (size_t)(g - NX - NQ) * 8;
      src = wp + e;
      dst = wpb + e;
    }
    float4 a = *(const float4*)src;
    float4 b = *(const float4*)(src + 4);
    ushort4 u0, u1;
    u0.x = f2b(a.x); u0.y = f2b(a.y); u0.z = f2b(a.z); u0.w = f2b(a.w);
    u1.x = f2b(b.x); u1.y = f2b(b.y); u1.z = f2b(b.z); u1.w = f2b(b.w);
    *(ushort4*)dst = u0;
    *(ushort4*)(dst + 4) = u1;
  }
}

// ---------------------------------------------------------------------------
// 256x256 8-phase GEMM (T2+T3+T4+T5), C = A @ B^T + bias. (unchanged r6)
// ---------------------------------------------------------------------------
template <int EPI>
__global__ __launch_bounds__(512, 2) void gemm256(
    const unsigned short* __restrict__ A, const unsigned short* __restrict__ B,
    const float* __restrict__ bias, const int* __restrict__ idx,
    unsigned short* __restrict__ outb, float* __restrict__ outf)
{
  __shared__ __align__(16) unsigned short lds[65536];  // 128 KiB
  const int t = threadIdx.x;
  const int lane = t & 63, wid = t >> 6;
  const int l15 = lane & 15, quad = lane >> 4;
  const int wr = wid >> 2, wc = wid & 3;
  const int bm = blockIdx.x, bn = blockIdx.y;

  const int srow = wid * 8 + (lane >> 3);
  const int scol = ((lane & 7) ^ (lane >> 3)) * 8;
  const unsigned short* gA = A + (size_t)(bm * 256 + srow) * EMBED + scol;
  const unsigned short* gB = B + (size_t)(bn * 256 + srow) * EMBED + scol;

  auto stA = [&](int p, int R0, int kt) {
    const unsigned short* g = gA + (size_t)R0 * EMBED + kt * 64;
    char* d = (char*)lds + p * 32768 + R0 * 128 + wid * 1024;
    gload16(g, d);
    gload16(g + (size_t)64 * EMBED, d + 8192);
  };
  auto stB = [&](int p, int R0, int kt) {
    const unsigned short* g = gB + (size_t)R0 * EMBED + kt * 64;
    char* d = (char*)lds + 65536 + p * 32768 + R0 * 128 + wid * 1024;
    gload16(g, d);
    gload16(g + (size_t)64 * EMBED, d + 8192);
  };

  const int aOff = (wr * 128 + l15) * 64;
  const int bOff = (wc * 64 + l15) * 64;
  const int swz0 = (quad ^ (l15 & 7)) * 8;
  const int swz1 = ((quad + 4) ^ (l15 & 7)) * 8;

  f32x4 acc[8][4];
#pragma unroll
  for (int i = 0; i < 8; ++i)
#pragma unroll
    for (int j = 0; j < 4; ++j) acc[i][j] = (f32x4){0.f, 0.f, 0.f, 0.f};

  stA(0, 0, 0); stA(0, 128, 0); stB(0, 0, 0); stB(0, 128, 0);
  stB(1, 0, 1); stB(1, 128, 1);
  asm volatile("s_waitcnt vmcnt(4)" ::: "memory");
  BARRIER();

#define MFMAGRP(MB)                                                          \
  _Pragma("unroll") for (int m = 0; m < 4; ++m)                              \
      _Pragma("unroll") for (int n = 0; n < 4; ++n)                          \
          acc[(MB) + m][n] = __builtin_amdgcn_mfma_f32_16x16x32_bf16(        \
              a[m], b[n], acc[(MB) + m][n], 0, 0, 0);

#define TILE(P, KT, STA, STB, WCNT)                                          \
  {                                                                          \
    const unsigned short* Ab = lds + (P) * 16384 + aOff;                     \
    const unsigned short* Bb = lds + 32768 + (P) * 16384 + bOff;             \
    bf16x8 a[4], b[4];                                                       \
    { /* phase 0: ks0, mt0-3 */                                              \
      _Pragma("unroll") for (int n = 0; n < 4; ++n)                          \
          b[n] = *(const bf16x8*)(Bb + n * 1024 + swz0);                     \
      _Pragma("unroll") for (int m = 0; m < 4; ++m)                          \
          a[m] = *(const bf16x8*)(Ab + m * 1024 + swz0);                     \
      if (STA) stA((P) ^ 1, 0, (KT) + 1);                                    \
      BARRIER();                                                             \
      __builtin_amdgcn_s_setprio(1);                                         \
      MFMAGRP(0);                                                            \
      __builtin_amdgcn_s_setprio(0);                                         \
      BARRIER();                                                             \
    }                                                                        \
    { /* phase 1: ks0, mt4-7 */                                              \
      _Pragma("unroll") for (int m = 0; m < 4; ++m)                          \
          a[m] = *(const bf16x8*)(Ab + (4 + m) * 1024 + swz0);               \
      if (STA) stA((P) ^ 1, 128, (KT) + 1);                                  \
      BARRIER();                                                             \
      __builtin_amdgcn_s_setprio(1);                                         \
      MFMAGRP(4);                                                            \
      __builtin_amdgcn_s_setprio(0);                                         \
      BARRIER();                                                             \
    }                                                                        \
    { /* phase 2: ks1, mt0-3 */                                              \
      _Pragma("unroll") for (int n = 0; n < 4; ++n)                          \
          b[n] = *(const bf16x8*)(Bb + n * 1024 + swz1);                     \
      _Pragma("unroll") for (int m = 0; m < 4; ++m)                          \
          a[m] = *(const bf16x8*)(Ab + m * 1024 + swz1);                     \
      if (STB) stB((P), 0, (KT) + 2);                                        \
      BARRIER();                                                             \
      __builtin_amdgcn_s_setprio(1);                                         \
      MFMAGRP(0);                                                            \
      __builtin_amdgcn_s_setprio(0);                                         \
      BARRIER();                                                             \
    }                                                                        \
    { /* phase 3: ks1, mt4-7 */                                              \
      _Pragma("unroll") for (int m = 0; m < 4; ++m)                          \
          a[m] = *(const bf16x8*)(Ab + (4 + m) * 1024 + swz1);               \
      if (STB) stB((P), 128, (KT) + 2);                                      \
      BARRIER();                                                             \
      __builtin_amdgcn_s_setprio(1);                                         \
      MFMAGRP(4);                                                            \
      __builtin_amdgcn_s_setprio(0);                                         \
      if ((WCNT) == 4) asm volatile("s_waitcnt vmcnt(4)" ::: "memory");      \
      if ((WCNT) == 0) asm volatile("s_waitcnt vmcnt(0)" ::: "memory");      \
      BARRIER();                                                             \
    }                                                                        \
  }

#pragma unroll 1
  for (int t2 = 0; t2 < 7; ++t2) {
    const int kt = t2 * 2;
    TILE(0, kt, 1, 1, 4);
    TILE(1, kt + 1, 1, 1, 4);
  }
  TILE(0, 14, 1, 0, 0);
  TILE(1, 15, 0, 0, -1);
#undef TILE
#undef MFMAGRP

  float bv[4];
#pragma unroll
  for (int nt = 0; nt < 4; ++nt)
    bv[nt] = bias[bn * 256 + wc * 64 + nt * 16 + l15];
  if constexpr (EPI == 0) {
    const int hh = bn * 4 + wc;
    unsigned short* buf = outb + (size_t)hh * (MTOT * HDIM);
#pragma unroll
    for (int mt = 0; mt < 8; ++mt) {
#pragma unroll
      for (int reg = 0; reg < 4; ++reg) {
        int row = bm * 256 + wr * 128 + mt * 16 + quad * 4 + reg;
        int i = idx[row];  // inv[]
#pragma unroll
        for (int nt = 0; nt < 4; ++nt)
          buf[(size_t)i * HDIM + nt * 16 + l15] =
              f2b(acc[mt][nt][reg] + bv[nt]);
      }
    }
  } else {
    const int col = bn * 256 + wc * 64;
#pragma unroll
    for (int mt = 0; mt < 8; ++mt) {
#pragma unroll
      for (int reg = 0; reg < 4; ++reg) {
        int i = bm * 256 + wr * 128 + mt * 16 + quad * 4 + reg;
        int orow = idx[i];  // kvi[]
        if (orow < LTOT) {
#pragma unroll
          for (int nt = 0; nt < 4; ++nt)
            outf[(size_t)orow * EMBED + col + nt * 16 + l15] =
                acc[mt][nt][reg] + bv[nt];
        }
      }
    }
  }
}

// ---------------------------------------------------------------------------
// rope_qk: in-place RoPE on qkvh head-slots 0..31 (Q scaled by 0.125).
// RESTORED (round-6 evidence: fusing RoPE into attn re-streams the 8 MB f32
// tables 16x — per-XCD L2 is 4 MB — costing +45 us vs this 25 us kernel).
// ---------------------------------------------------------------------------
__global__ __launch_bounds__(256) void rope_qk(
    const float* __restrict__ rope_cos, const float* __restrict__ rope_sin,
    unsigned short* __restrict__ qkvh)
{
  int g = blockIdx.x * 256 + threadIdx.x;
  int dc = g & 3;
  int i  = (g >> 2) & (MTOT - 1);
  int hh = g >> 16;
  unsigned short* p = qkvh + ((size_t)hh * MTOT + i) * HDIM;
  bf16x8 lo = *(const bf16x8*)(p + dc * 8);
  bf16x8 hi = *(const bf16x8*)(p + 32 + dc * 8);
  const float* cp = rope_cos + (size_t)i * HDIM + dc * 8;
  const float* sp = rope_sin + (size_t)i * HDIM + dc * 8;
  float cl[8], ch[8], sl[8], sh[8];
  *(float4*)(cl)     = *(const float4*)(cp);
  *(float4*)(cl + 4) = *(const float4*)(cp + 4);
  *(float4*)(ch)     = *(const float4*)(cp + 32);
  *(float4*)(ch + 4) = *(const float4*)(cp + 36);
  *(float4*)(sl)     = *(const float4*)(sp);
  *(float4*)(sl + 4) = *(const float4*)(sp + 4);
  *(float4*)(sh)     = *(const float4*)(sp + 32);
  *(float4*)(sh + 4) = *(const float4*)(sp + 36);
  const float sc = (hh < 16) ? 0.125f : 1.0f;
  bf16x8 olo, ohi;
#pragma unroll
  for (int j = 0; j < 8; ++j) {
    float a = b2f((unsigned short)lo[j]);
    float b = b2f((unsigned short)hi[j]);
    olo[j] = (short)f2b((a * cl[j] - b * sl[j]) * sc);
    ohi[j] = (short)f2b((b * ch[j] + a * sh[j]) * sc);
  }
  *(bf16x8*)(p + dc * 8) = olo;
  *(bf16x8*)(p + 32 + dc * 8) = ohi;
}

// ---------------------------------------------------------------------------
// cast_w: proj_w fp32 -> bf16 (fallback path when ws has no spare region).
// ---------------------------------------------------------------------------
__global__ __launch_bounds__(256) void cast_w(
    const float* __restrict__ w, unsigned short* __restrict__ wb)
{
  int g = blockIdx.x * 256 + threadIdx.x;
  size_t e = (size_t)g * 8;
  float4 a = *(const float4*)(w + e);
  float4 b = *(const float4*)(w + e + 4);
  ushort4 u0, u1;
  u0.x = f2b(a.x); u0.y = f2b(a.y); u0.z = f2b(a.z); u0.w = f2b(a.w);
  u1.x = f2b(b.x); u1.y = f2b(b.y); u1.z = f2b(b.z); u1.w = f2b(b.w);
  *(ushort4*)(wb + e) = u0;
  *(ushort4*)(wb + e + 4) = u1;
}

// ---------------------------------------------------------------------------
// Attention: one block per (window, head). Round-7: latency attack (T14/T3).
//  - attn was latency-bound (r6: MfmaUtil 4.8%, VALU 18%, HBM 40%, occ 24% —
//    nothing saturated; floor ~30 us vs 142 measured). The serial chain was
//    {stage K/V -> barrier -> compute} x2 with exposed ~600cy global latency.
//  - sK/sV double-buffered (LDS 69 KB, 2 blocks/CU): half-1 K/V loads issue
//    BEFORE half-0 compute and land during it.
//  - K staged via global_load_lds with pre-swizzled per-lane SOURCE (rule
//    #21): pure async DMA, no VGPR roundtrip (K pre-roped by rope_qk again).
//  - V reg-staged (transpose needs scatter), loads issued early, scalar LDS
//    writes after the vmcnt wait.
//  - __launch_bounds__(256,2): LDS caps at 2 blocks/CU anyway; take the
//    256-reg budget so vr1 live-across-compute cannot spill.
// ---------------------------------------------------------------------------
__global__ __launch_bounds__(256, 2) void attn(
    const unsigned short* __restrict__ qkvh,
    unsigned short* __restrict__ ow)
{
  __shared__ __align__(16) unsigned short sK[2][128 * 64];
  __shared__ __align__(16) unsigned short sV[2][64 * 128];
  __shared__ __align__(16) unsigned short sP[4][16 * 40];

  const int t = threadIdx.x;
  const int lane = t & 63, wid = t >> 6;
  const int l15 = lane & 15, quad = lane >> 4;
  const int wwin = blockIdx.x >> 4;
  const int h = blockIdx.x & 15;

  const unsigned short* Qh = qkvh + (size_t)h * (MTOT * HDIM);
  const unsigned short* Kh = qkvh + (size_t)(16 + h) * (MTOT * HDIM);
  const unsigned short* Vh = qkvh + (size_t)(32 + h) * (MTOT * HDIM);

  // --- K staging: async global_load_lds, linear LDS dest + inverse-swizzled
  // per-lane global source. Wave w covers keys [w*32, w*32+32), 4 passes of
  // 8 keys (64 lanes x 16B = 8 keys x 8 chunks). LDS slot (key, s) receives
  // K[i_key][(s ^ (key&7))*8 ..]; here key&7 == lane>>3.
  const int l3 = lane >> 3, l7 = lane & 7;
  const unsigned short* ksrc =
      Kh + (size_t)(wwin * 256 + wid * 32 + l3) * HDIM + (l7 ^ l3) * 8;
  auto stageK = [&](int buf, int half) {
#pragma unroll
    for (int p = 0; p < 4; ++p)
      gload16(ksrc + (size_t)(half * 128 + p * 8) * HDIM,
              (char*)&sK[buf][(wid * 32 + p * 8) * 64]);
  };

  // --- V: reg-staged; thread (vkey, vhx) owns d in [vhx*32, vhx*32+32).
  const int vkey = t >> 1, vhx = t & 1;
  const unsigned short* vsrc =
      Vh + (size_t)(wwin * 256 + vkey) * HDIM + vhx * 32;
  auto writeV = [&](int buf, bf16x8* vr) {
    int kc3 = vkey >> 3, k7 = vkey & 7;
#pragma unroll
    for (int c = 0; c < 4; ++c)
#pragma unroll
      for (int j = 0; j < 8; ++j) {
        int d = vhx * 32 + c * 8 + j;
        sV[buf][d * 128 + ((kc3 ^ (d & 7)) * 8) + k7] =
            (unsigned short)vr[c][j];
      }
  };

  f32x4 accO[4][4];
  float mrow[4][4], lrow[4][4];
#pragma unroll
  for (int qt = 0; qt < 4; ++qt) {
#pragma unroll
    for (int nt = 0; nt < 4; ++nt) accO[qt][nt] = (f32x4){0.f, 0.f, 0.f, 0.f};
#pragma unroll
    for (int reg = 0; reg < 4; ++reg) { mrow[qt][reg] = -1e30f; lrow[qt][reg] = 0.f; }
  }

  // prologue: issue half-0 K DMA + V/Q reg loads (latencies all overlap)
  stageK(0, 0);
  bf16x8 vr0[4], vr1[4];
#pragma unroll
  for (int c = 0; c < 4; ++c) vr0[c] = *(const bf16x8*)(vsrc + c * 8);
  bf16x8 qa[4][2];
#pragma unroll
  for (int qt = 0; qt < 4; ++qt) {
    int i = wwin * 256 + wid * 64 + qt * 16 + l15;
    const unsigned short* qp = Qh + (size_t)i * HDIM;
    qa[qt][0] = *(const bf16x8*)(qp + quad * 8);
    qa[qt][1] = *(const bf16x8*)(qp + 32 + quad * 8);
  }
  asm volatile("s_waitcnt vmcnt(0)" ::: "memory");  // K0 in LDS; vr0/qa in regs
  writeV(0, vr0);
  stageK(1, 1);                                     // half-1 K DMA in flight
#pragma unroll
  for (int c = 0; c < 4; ++c)                       // half-1 V loads in flight
    vr1[c] = *(const bf16x8*)(vsrc + (size_t)128 * HDIM + c * 8);
  __syncthreads();                                  // sK[0], sV[0] complete

  auto compute = [&](const unsigned short* sKb, const unsigned short* sVb) {
#pragma unroll
    for (int qt = 0; qt < 4; ++qt) {
      f32x4 accS[8];
#pragma unroll
      for (int nt = 0; nt < 8; ++nt) accS[nt] = (f32x4){0.f, 0.f, 0.f, 0.f};
#pragma unroll
      for (int ks = 0; ks < 2; ++ks) {
#pragma unroll
        for (int nt = 0; nt < 8; ++nt) {
          int key = nt * 16 + l15;
          bf16x8 bk = *(const bf16x8*)(
              sKb + key * 64 + (((ks * 4 + quad) ^ (key & 7)) * 8));
          accS[nt] = __builtin_amdgcn_mfma_f32_16x16x32_bf16(
              qa[qt][ks], bk, accS[nt], 0, 0, 0);
        }
      }
#pragma unroll
      for (int reg = 0; reg < 4; ++reg) {
        float mx = accS[0][reg];
#pragma unroll
        for (int nt = 1; nt < 8; ++nt) mx = fmaxf(mx, accS[nt][reg]);
#pragma unroll
        for (int off = 1; off < 16; off <<= 1)
          mx = fmaxf(mx, __shfl_xor(mx, off, 64));
        float mold = mrow[qt][reg];
        float mnew = fmaxf(mold, mx);
        float alpha = __expf(mold - mnew);
        mrow[qt][reg] = mnew;
        float ls = 0.f;
#pragma unroll
        for (int nt = 0; nt < 8; ++nt) {
          float p = __expf(accS[nt][reg] - mnew);
          accS[nt][reg] = p;
          ls += p;
        }
#pragma unroll
        for (int off = 1; off < 16; off <<= 1) ls += __shfl_xor(ls, off, 64);
        lrow[qt][reg] = lrow[qt][reg] * alpha + ls;
#pragma unroll
        for (int nt = 0; nt < 4; ++nt) accO[qt][nt][reg] *= alpha;
      }
#pragma unroll
      for (int kc = 0; kc < 4; ++kc) {
#pragma unroll
        for (int nt2 = 0; nt2 < 2; ++nt2) {
#pragma unroll
          for (int reg = 0; reg < 4; ++reg) {
            sP[wid][(quad * 4 + reg) * 40 + nt2 * 16 + l15] =
                f2b(accS[kc * 2 + nt2][reg]);
          }
        }
        bf16x8 pa = *(const bf16x8*)(&sP[wid][l15 * 40 + quad * 8]);
#pragma unroll
        for (int nt = 0; nt < 4; ++nt) {
          int d = nt * 16 + l15;
          bf16x8 bv = *(const bf16x8*)(
              sVb + d * 128 + (((kc * 4 + quad) ^ (d & 7)) * 8));
          accO[qt][nt] = __builtin_amdgcn_mfma_f32_16x16x32_bf16(
              pa, bv, accO[qt][nt], 0, 0, 0);
        }
      }
    }
  };

  compute(&sK[0][0], &sV[0][0]);                    // half-1 loads land here
  asm volatile("s_waitcnt vmcnt(0)" ::: "memory");  // K1 in LDS; vr1 arrived
  __syncthreads();                                  // all waves' K1 complete
  writeV(1, vr1);
  __syncthreads();                                  // sV[1] complete
  compute(&sK[1][0], &sV[1][0]);

  // ---- vectorized epilogue: per-wave LDS transpose, 16B/lane stores ----
  __syncthreads();                          // compute done; sK[0] = scratch
  unsigned short* scr = &sK[0][0] + wid * 2048;
  const int rlane = lane >> 3;
  const int clane = (lane & 7) * 8;
#pragma unroll
  for (int qt = 0; qt < 4; ++qt) {
#pragma unroll
    for (int reg = 0; reg < 4; ++reg) {
      float invl = 1.0f / lrow[qt][reg];
      int r = quad * 4 + reg;
#pragma unroll
      for (int nt = 0; nt < 4; ++nt)
        scr[r * 72 + nt * 16 + l15] = f2b(accO[qt][nt][reg] * invl);
    }
#pragma unroll
    for (int rr = 0; rr < 2; ++rr) {
      int row = rr * 8 + rlane;
      bf16x8 vv = *(const bf16x8*)(scr + row * 72 + clane);
      int i = wwin * 256 + wid * 64 + qt * 16 + row;
      *(bf16x8*)(ow + (size_t)i * EMBED + h * HDIM + clane) = vv;
    }
  }
}

// ---------------------------------------------------------------------------
extern "C" void kernel_launch(void* const* d_in, const int* in_sizes, int n_in,
                              void* d_out, int out_size, void* d_ws, size_t ws_size,
                              hipStream_t stream) {
  const float* x        = (const float*)d_in[0];
  const float* qkv_w    = (const float*)d_in[1];
  const float* qkv_b    = (const float*)d_in[2];
  const float* proj_w   = (const float*)d_in[3];
  const float* proj_b   = (const float*)d_in[4];
  const float* padding  = (const float*)d_in[5];
  const float* rope_cos = (const float*)d_in[6];
  const float* rope_sin = (const float*)d_in[7];
  const int*   kvi      = (const int*)d_in[8];

  // ws layout:
  //   [0, 100.66M):       qkvh — head-major, window-permuted [48][16384][64]
  //                       bf16; roped in-place by rope_qk.
  //   [100.66M, +33.55M): xb (cast+gemm_qkv) then ow (attn output,
  //                       window-permuted [16384][1024] bf16, gemm_proj A)
  //   [134.22M, +2M):     wpb (proj_w bf16) IF ws_size permits; else wpb
  //                       falls back to the dead Q region + cast_w launch.
  // d_out scratch: head: wqb (6.3 MB); tail: inv (64 KB int32) — both read
  // only by gemm_qkv, which completes before gemm_proj (stream order).
  const size_t QKVH_B = (size_t)MTOT * THREE_EMBED * 2;   // 100,663,296
  const size_t R_B    = (size_t)MTOT * EMBED * 2;         //  33,554,432
  const size_t W_B    = (size_t)EMBED * EMBED * 2;        //   2,097,152
  unsigned short* qkvh = (unsigned short*)d_ws;
  unsigned short* R    = (unsigned short*)((char*)d_ws + QKVH_B);
  unsigned short* xb = R;
  unsigned short* ow = R;
  unsigned short* wqb = (unsigned short*)d_out;
  const bool roomy = ws_size >= QKVH_B + R_B + W_B;
  unsigned short* wpb = roomy
      ? (unsigned short*)((char*)d_ws + QKVH_B + R_B)
      : qkvh;  // Q region, dead after attn (fallback)
  int* inv = (int*)((char*)d_out + (size_t)LTOT * EMBED * 4 - (size_t)MTOT * 4);
  float* out = (float*)d_out;

  cast_inputs<<<4096, 256, 0, stream>>>(
      x, padding, qkv_w, roomy ? proj_w : nullptr, kvi, xb, wqb, wpb, inv,
      roomy ? (EMBED * EMBED / 8) : 0);
  gemm256<0><<<dim3(64, 12), 512, 0, stream>>>(xb, wqb, qkv_b, inv, qkvh,
                                               nullptr);
  rope_qk<<<8192, 256, 0, stream>>>(rope_cos, rope_sin, qkvh);
  attn<<<dim3(64 * 16), 256, 0, stream>>>(qkvh, ow);
  if (!roomy) cast_w<<<512, 256, 0, stream>>>(proj_w, wpb);
  gemm256<1><<<dim3(64, 4), 512, 0, stream>>>(ow, wpb, proj_b, kvi, nullptr,
                                              out);
}